// Round 8
// baseline (3083.694 us; speedup 1.0000x reference)
//
#include <hip/hip_runtime.h>
#include <math.h>

#define AS1 __attribute__((address_space(1)))
#define AS3 __attribute__((address_space(3)))

typedef __attribute__((ext_vector_type(8))) short short8v;
typedef __attribute__((ext_vector_type(16))) float f32x16;

constexpr size_t PA4c = (size_t)4096 * 512;   // plane stride, M=4096 activations
constexpr size_t PABc = (size_t)256 * 512;    // plane stride, M=256 activations

__device__ __forceinline__ float sigmoidf_(float x) { return 1.f / (1.f + expf(-x)); }
__device__ __forceinline__ unsigned int f2bfu(float f) {
    unsigned int u = __float_as_uint(f);
    return (u + 0x7FFF + ((u >> 16) & 1)) >> 16;
}
__device__ __forceinline__ float bf2f(unsigned int s) { return __uint_as_float(s << 16); }
__device__ __forceinline__ unsigned int pack2(float v) {
    unsigned int b0 = f2bfu(v);
    unsigned int b1 = f2bfu(v - bf2f(b0));
    return b0 | (b1 << 16);
}
__device__ __forceinline__ float unpack2(unsigned int p) { return bf2f(p & 0xffffu) + bf2f(p >> 16); }

__device__ __forceinline__ void xswz(int d, int ngx, int ngy, int& bx, int& by) {
    int nwg = ngx * ngy;
    int q = nwg >> 3, r = nwg & 7, xcd = d & 7, pos = d >> 3;
    int logical = (xcd < r ? xcd * (q + 1) : r * (q + 1) + (xcd - r) * q) + pos;
    bx = logical % ngx; by = logical / ngx;
}

// blocked activation-plane offset for (m, k)
__device__ __forceinline__ size_t offf(int m, int k) {
    return ((size_t)((m >> 5) * 64 + (k >> 3))) * 256 + (size_t)((m & 31) * 8 + (k & 7));
}

// write-through 2-byte store (visible at coherent point, no dirty L2 line)
__device__ __forceinline__ void store2_coh(unsigned short* p, unsigned int v) {
    asm volatile("global_store_short %0, %1, off sc0 sc1" :: "v"(p), "v"(v) : "memory");
}

template<int N>
__device__ __forceinline__ void wait_vm() {
    asm volatile("s_waitcnt vmcnt(%0) lgkmcnt(0)" :: "n"(N) : "memory");
}

// ================= GEMM core: 2-plane/3-product, 8 waves (4m x 2n), BK=32, NBUF-deep counted vmcnt ====
template<int FM, int FN, int NBUF, bool COHB>
__device__ __forceinline__ void gemm_core(
    const short* __restrict__ A1, const short* __restrict__ B1,
    const short* __restrict__ A2, const short* __restrict__ B2,
    int M, int N, int nsteps, int pairSwitch,
    int bx, int by, short* lds, f32x16 (&acc)[FM][FN])
{
    constexpr int ABLK = 4 * FM, BBLK = 2 * FN;
    constexpr int ACH = 2 * ABLK * 2, BCH = 2 * BBLK * 2;
    constexpr int CHT = ACH + BCH;
    constexpr int CPW = CHT / 8;
    constexpr int BUFSH = CHT * 512;
    const int tid = threadIdx.x, lane = tid & 63, wid = tid >> 6;
    const int wm = wid >> 1, wn = wid & 1;
    const int l31 = lane & 31, loct = lane >> 5;
    const int mblk0 = by * ABLK, nblk0 = bx * BBLK;
    const size_t planeA = (size_t)M * 512, planeB = (size_t)N * 512;

    const short* cur[CPW];
    const short* nxt[CPW];
    int ldo[CPW];
    bool isB[CPW];
    #pragma unroll
    for (int i = 0; i < CPW; ++i) {
        int c = wid * CPW + i;
        ldo[i] = c * 512;
        size_t off;
        const short *b1, *b2;
        if (c < ACH) {
            int plane = c / (ABLK * 2), rem = c % (ABLK * 2), blk = rem >> 1, piece = rem & 1;
            off = (size_t)plane * planeA + (size_t)(mblk0 + blk) * 16384 + piece * 512 + lane * 8;
            b1 = A1; b2 = A2; isB[i] = false;
        } else {
            int cb = c - ACH;
            int plane = cb / (BBLK * 2), rem = cb % (BBLK * 2), blk = rem >> 1, piece = rem & 1;
            off = (size_t)plane * planeB + (size_t)(nblk0 + blk) * 16384 + piece * 512 + lane * 8;
            b1 = B1; b2 = B2; isB[i] = true;
        }
        cur[i] = b1 + off;
        nxt[i] = b2 ? (b2 + off) : (b1 + off);
    }

    #pragma unroll
    for (int fm = 0; fm < FM; ++fm)
        #pragma unroll
        for (int fn = 0; fn < FN; ++fn)
            acc[fm][fn] = (f32x16){};

    auto STAGE = [&](int bufIdx) {
        short* db = lds + bufIdx * BUFSH;
        #pragma unroll
        for (int i = 0; i < CPW; ++i) {
            if constexpr (COHB) {
                if (isB[i])
                    __builtin_amdgcn_global_load_lds((const AS1 unsigned int*)cur[i],
                                                     (AS3 unsigned int*)(db + ldo[i]), 16, 0, 17);
                else
                    __builtin_amdgcn_global_load_lds((const AS1 unsigned int*)cur[i],
                                                     (AS3 unsigned int*)(db + ldo[i]), 16, 0, 0);
            } else {
                __builtin_amdgcn_global_load_lds((const AS1 unsigned int*)cur[i],
                                                 (AS3 unsigned int*)(db + ldo[i]), 16, 0, 0);
            }
            cur[i] += 1024;
        }
    };

    #pragma unroll
    for (int i = 0; i < NBUF - 1; ++i) STAGE(i);
    wait_vm<CPW * (NBUF - 2)>();
    __builtin_amdgcn_s_barrier();

    for (int t = 0; t < nsteps; ++t) {
        int s = t + NBUF - 1;
        if (s < nsteps) {
            if (s == pairSwitch) {
                #pragma unroll
                for (int i = 0; i < CPW; ++i) cur[i] = nxt[i];
            }
            STAGE(s % NBUF);
        }
        const short* L = lds + (t % NBUF) * BUFSH;
        #pragma unroll
        for (int ksub = 0; ksub < 2; ++ksub) {
            short8v a[FM][2], b[FN][2];
            #pragma unroll
            for (int p = 0; p < 2; ++p) {
                #pragma unroll
                for (int f = 0; f < FM; ++f)
                    a[f][p] = *(const short8v*)(L + (p * (ABLK * 2) + (wm * FM + f) * 2 + ksub) * 512
                                                  + loct * 256 + l31 * 8);
                #pragma unroll
                for (int f = 0; f < FN; ++f)
                    b[f][p] = *(const short8v*)(L + (ACH + p * (BBLK * 2) + (wn * FN + f) * 2 + ksub) * 512
                                                  + loct * 256 + l31 * 8);
            }
            #pragma unroll
            for (int pp = 0; pp < 3; ++pp) {
                const int pa = (pp == 2) ? 1 : 0, pb = (pp == 1) ? 1 : 0;
                #pragma unroll
                for (int fm = 0; fm < FM; ++fm)
                    #pragma unroll
                    for (int fn = 0; fn < FN; ++fn)
                        acc[fm][fn] = __builtin_amdgcn_mfma_f32_32x32x16_bf16(
                            a[fm][pa], b[fn][pb], acc[fm][fn], 0, 0, 0);
            }
        }
        int ahead = nsteps - 2 - t;
        if (ahead >= NBUF - 2)      wait_vm<CPW * (NBUF - 2)>();
        else if (ahead == 3)        wait_vm<CPW * 3>();
        else if (ahead == 2)        wait_vm<CPW * 2>();
        else if (ahead == 1)        wait_vm<CPW * 1>();
        else                        wait_vm<0>();
        __builtin_amdgcn_s_barrier();
    }
}

// ---------------- epilogues (C/D layout: col=lane&31, row=(reg&3)+8*(reg>>2)+4*(lane>>5)) ----------------
template<int FM, int FN>
__device__ __forceinline__ void epi_f32(f32x16 (&acc)[FM][FN], int bx, int by, int N,
                                        float* __restrict__ Cout, const float* __restrict__ bias, int act)
{
    constexpr int ROWS = 128 * FM, COLS = 64 * FN;
    const int tid = threadIdx.x, lane = tid & 63, wid = tid >> 6;
    const int wm = wid >> 1, wn = wid & 1, l31 = lane & 31, loct = lane >> 5;
    #pragma unroll
    for (int fm = 0; fm < FM; ++fm)
        #pragma unroll
        for (int fn = 0; fn < FN; ++fn) {
            int col = bx * COLS + wn * FN * 32 + fn * 32 + l31;
            int rb  = by * ROWS + wm * FM * 32 + fm * 32 + 4 * loct;
            #pragma unroll
            for (int reg = 0; reg < 16; ++reg) {
                int row = rb + (reg & 3) + 8 * (reg >> 2);
                float xv = acc[fm][fn][reg] + (bias ? bias[row] : 0.f);
                if (act) xv = tanhf(xv);
                Cout[(size_t)row * N + col] = xv;
            }
        }
}

template<int FM, int FN>
__device__ __forceinline__ void epi_pack(f32x16 (&acc)[FM][FN], int bx, int by, int N,
                                         unsigned int* __restrict__ packOut)
{
    constexpr int ROWS = 128 * FM, COLS = 64 * FN;
    const int tid = threadIdx.x, lane = tid & 63, wid = tid >> 6;
    const int wm = wid >> 1, wn = wid & 1, l31 = lane & 31, loct = lane >> 5;
    uint4* P4 = (uint4*)packOut;
    #pragma unroll
    for (int fm = 0; fm < FM; ++fm)
        #pragma unroll
        for (int fn = 0; fn < FN; ++fn) {
            int col = bx * COLS + wn * FN * 32 + fn * 32 + l31;
            int ub = by * (ROWS / 4) + wm * FM * 8 + fm * 8 + loct;
            #pragma unroll
            for (int ug = 0; ug < 4; ++ug) {
                int u = ub + 2 * ug;
                uint4 v;
                v.x = pack2(acc[fm][fn][4 * ug + 0]);
                v.y = pack2(acc[fm][fn][4 * ug + 1]);
                v.z = pack2(acc[fm][fn][4 * ug + 2]);
                v.w = pack2(acc[fm][fn][4 * ug + 3]);
                P4[(size_t)u * N + col] = v;
            }
        }
}

// fused LSTM gate epilogue, batched loads (decoder)
template<int FM, int FN>
__device__ __forceinline__ void epi_gate2(
    f32x16 (&acc)[FM][FN], int bx, int by, int N, short* hl,
    const float* __restrict__ bab,
    const unsigned int* __restrict__ hgP,
    const unsigned int* __restrict__ embT,
    const int* __restrict__ xidx,
    float* __restrict__ cT,
    short* __restrict__ hout, size_t hps)
{
    constexpr int ABLK = 4 * FM, BBLK = 2 * FN;
    constexpr int ROWS = 32 * ABLK, COLS = 32 * BBLK;
    constexpr int CHN = ABLK * BBLK * 256;
    const int tid = threadIdx.x, lane = tid & 63, wid = tid >> 6;
    const int wm = wid >> 1, wn = wid & 1, l31 = lane & 31, loct = lane >> 5;
    #pragma unroll
    for (int fm = 0; fm < FM; ++fm) {
        #pragma unroll
        for (int fn = 0; fn < FN; ++fn) {
            const int col = bx * COLS + wn * FN * 32 + fn * 32 + l31;
            const int ub = by * (ROWS / 4) + wm * FM * 8 + fm * 8 + loct;
            int tok = -1;
            if (xidx) tok = xidx[(size_t)col * 16];
            uint4 hv[4]; uint4 ev[4]; float cv[4]; float4 bv[4];
            #pragma unroll
            for (int ug = 0; ug < 4; ++ug) {
                int u = ub + 2 * ug;
                bv[ug] = *(const float4*)&bab[4 * u];
                cv[ug] = cT[(size_t)u * N + col];
                if (hgP) hv[ug] = ((const uint4*)hgP)[(size_t)u * N + col];
            }
            if (embT && tok >= 0) {
                #pragma unroll
                for (int ug = 0; ug < 4; ++ug) {
                    int u = ub + 2 * ug;
                    ev[ug] = ((const uint4*)embT)[(size_t)u * 512 + tok];
                }
            }
            #pragma unroll
            for (int ug = 0; ug < 4; ++ug) {
                int u = ub + 2 * ug;
                float gi = acc[fm][fn][4 * ug + 0] + bv[ug].x;
                float gf = acc[fm][fn][4 * ug + 1] + bv[ug].y;
                float gg = acc[fm][fn][4 * ug + 2] + bv[ug].z;
                float go = acc[fm][fn][4 * ug + 3] + bv[ug].w;
                if (hgP) {
                    gi += unpack2(hv[ug].x); gf += unpack2(hv[ug].y);
                    gg += unpack2(hv[ug].z); go += unpack2(hv[ug].w);
                }
                if (embT && tok >= 0) {
                    gi += unpack2(ev[ug].x); gf += unpack2(ev[ug].y);
                    gg += unpack2(ev[ug].z); go += unpack2(ev[ug].w);
                }
                float c = sigmoidf_(gf) * cv[ug] + sigmoidf_(gi) * tanhf(gg);
                cT[(size_t)u * N + col] = c;
                float h = sigmoidf_(go) * tanhf(c);
                unsigned int p01 = pack2(h);
                int u_loc = wm * FM * 8 + fm * 8 + loct + 2 * ug;
                int m_loc = wn * FN * 32 + fn * 32 + l31;
                int offl = ((m_loc >> 5) * ABLK + (u_loc >> 3)) * 256 + (m_loc & 31) * 8 + (u_loc & 7);
                hl[offl] = (short)(p01 & 0xffffu);
                hl[CHN + offl] = (short)(p01 >> 16);
            }
        }
    }
    __syncthreads();
    constexpr int LB = (ABLK == 8) ? 3 : 2;
    for (int p = 0; p < 2; ++p) {
        for (int jj = tid; jj < CHN / 8; jj += 512) {
            int lc = jj >> 5, m31 = jj & 31;
            int m5 = lc >> LB, u3 = lc & (ABLK - 1);
            size_t gc = (size_t)((bx * BBLK + m5) * 64 + by * ABLK + u3);
            *(short8v*)(hout + p * hps + gc * 256 + m31 * 8) = *(const short8v*)(hl + p * CHN + jj * 8);
        }
    }
}

// ================= relaxed device barrier: no release/acquire fence, no L2 flush =================
__device__ __forceinline__ void devbar2(unsigned int* cnt, unsigned int target)
{
    asm volatile("s_waitcnt vmcnt(0)" ::: "memory");   // drain write-through stores
    __syncthreads();
    if (threadIdx.x == 0) {
        __hip_atomic_fetch_add(cnt, 1u, __ATOMIC_RELAXED, __HIP_MEMORY_SCOPE_AGENT);
        int budget = 1 << 22;
        while (__hip_atomic_load(cnt, __ATOMIC_RELAXED, __HIP_MEMORY_SCOPE_AGENT) < target && --budget)
            __builtin_amdgcn_s_sleep(1);
    }
    __syncthreads();
}

// ================= standalone GEMM kernels =================
template<int FM, int FN>
__global__ __launch_bounds__(512, 1) void gemm_packk(
    const short* A1, const short* B1, const short* A2, const short* B2,
    int M, int N, int nsteps, int psw, unsigned int* packOut)
{
    __shared__ __align__(16) short lds[3 * (2 * (4 * FM) * 2 + 2 * (2 * FN) * 2) * 512];
    int d = blockIdx.y * gridDim.x + blockIdx.x;
    int bx, by; xswz(d, gridDim.x, gridDim.y, bx, by);
    f32x16 acc[FM][FN];
    gemm_core<FM, FN, 3, false>(A1, B1, A2, B2, M, N, nsteps, psw, bx, by, lds, acc);
    epi_pack<FM, FN>(acc, bx, by, N, packOut);
}

template<int FM, int FN>
__global__ __launch_bounds__(512, 1) void gemm_split(
    const short* A1, const short* B1, int M, int N, int nsteps,
    const float* bias, short* hA, short* hB, size_t ps, float* cA, float* cB)
{
    __shared__ __align__(16) short lds[3 * (2 * (4 * FM) * 2 + 2 * (2 * FN) * 2) * 512];
    int d = blockIdx.y * gridDim.x + blockIdx.x;
    int bx, by; xswz(d, gridDim.x, gridDim.y, bx, by);
    f32x16 acc[FM][FN];
    gemm_core<FM, FN, 3, false>(A1, B1, nullptr, nullptr, M, N, nsteps, 100, bx, by, lds, acc);
    constexpr int ROWS = 128 * FM, COLS = 64 * FN;
    const int tid = threadIdx.x, lane = tid & 63, wid = tid >> 6;
    const int wm = wid >> 1, wn = wid & 1, l31 = lane & 31, loct = lane >> 5;
    #pragma unroll
    for (int fm = 0; fm < FM; ++fm)
        #pragma unroll
        for (int fn = 0; fn < FN; ++fn) {
            int col = bx * COLS + wn * FN * 32 + fn * 32 + l31;
            int rb  = by * ROWS + wm * FM * 32 + fm * 32 + 4 * loct;
            #pragma unroll
            for (int reg = 0; reg < 16; ++reg) {
                int row = rb + (reg & 3) + 8 * (reg >> 2);
                float xv = tanhf(acc[fm][fn][reg] + bias[row]);
                if (row < 1024) {
                    short* hp = (row < 512) ? hA : hB;
                    size_t o = offf(col, row & 511);
                    unsigned int p01 = pack2(xv);
                    hp[o] = (short)(p01 & 0xffffu);
                    hp[ps + o] = (short)(p01 >> 16);
                } else {
                    float* cp = (row < 1536) ? cA : cB;
                    cp[(size_t)(row & 511) * N + col] = xv;
                }
            }
        }
}

// ================= persistent conditioning LSTM v4: B-tile burst into LDS, warm-L2 A stream ===========
// 128 blocks x 256 thr (4 waves). Tile 128 rows x 32 cols. LDS: B 128KB + A 3x8KB = 152 KB.
__global__ __launch_bounds__(256, 1) void cond_lstm(
    const short* cWih0P, const short* cWhh0P, const short* cWih1P, const short* cWhh1P,
    const float* babc0, const float* babc1,
    const float* c1T0, const float* c2T0,
    short* h1p0, short* h1p1, short* h2p0, short* h2p1,
    short* condp, unsigned int* bar)
{
    __shared__ __align__(16) short Blds[2][2][16384];   // [mat][plane][32col x 512K]  128 KB
    __shared__ __align__(16) short Alds[3][4096];       // [buf][2pl x 4blk x 2kp x 256]  24 KB

    const int d = blockIdx.x;                 // 128 blocks
    const int xcd = d & 7, slot = d >> 3;     // 16 slots per XCD
    const int by = xcd * 2 + (slot & 1);      // [0,16)  128-row slice (XCD-pinned rows)
    const int bx = slot >> 1;                 // [0,8)   32-col slice
    const int tid = threadIdx.x;
    const int lane = tid & 63, wid = tid >> 6;    // 4 waves
    const int l31 = lane & 31, loct = lane >> 5;
    const int mblk0 = by * 4;
    const int col = bx * 32 + l31;
    const int ub = by * 32 + wid * 8 + loct;

    float c1r[4], c2r[4];
    #pragma unroll
    for (int ug = 0; ug < 4; ++ug) {
        int u = ub + 2 * ug;
        c1r[ug] = c1T0[(size_t)u * 256 + col];
        c2r[ug] = c2T0[(size_t)u * 256 + col];
    }

    unsigned int gen = 0;
    for (int s = 0; s < 16; ++s) {
        const int pin = s & 1;
        const short* h1in = pin ? h1p1 : h1p0;  short* h1out = pin ? h1p0 : h1p1;
        const short* h2in = pin ? h2p1 : h2p0;  short* h2out = pin ? h2p0 : h2p1;

        for (int cell = 0; cell < 2; ++cell) {
            const short* Am[2]; const short* Bm[2]; int nmat;
            if (cell == 0) {
                if (s == 0) { Am[0] = cWhh0P; Bm[0] = h1in; Am[1] = cWhh0P; Bm[1] = h1in; nmat = 1; }
                else        { Am[0] = cWih0P; Bm[0] = h2in; Am[1] = cWhh0P; Bm[1] = h1in; nmat = 2; }
            } else {
                Am[0] = cWih1P; Bm[0] = h1out; Am[1] = cWhh1P; Bm[1] = h2in; nmat = 2;
            }
            // ---- burst B tiles into LDS (coherent reads of freshly exchanged h) ----
            for (int m = 0; m < nmat; ++m) {
                #pragma unroll
                for (int i = 0; i < 16; ++i) {
                    int q = tid + i * 256;             // [0,4096)
                    int pl = q >> 11, r = q & 2047;
                    __builtin_amdgcn_global_load_lds(
                        (const AS1 unsigned int*)(Bm[m] + (size_t)pl * PABc + bx * 16384 + r * 8),
                        (AS3 unsigned int*)(&Blds[m][pl][r * 8]), 16, 0, 17);
                }
            }
            const int T = nmat * 32;   // ksteps of K=16
            auto stageA = [&](int t) {
                const short* Ab = Am[t >> 5];
                int tk = t & 31;
                #pragma unroll
                for (int i = 0; i < 2; ++i) {
                    int q = tid + i * 256;             // [0,512)
                    int pl = q >> 8, blk = (q >> 6) & 3, kp = (q >> 5) & 1, lp = q & 31;
                    __builtin_amdgcn_global_load_lds(
                        (const AS1 unsigned int*)(Ab + (size_t)pl * ((size_t)2048 * 512)
                                                  + (size_t)(mblk0 + blk) * 16384 + (tk * 2 + kp) * 256 + lp * 8),
                        (AS3 unsigned int*)(&Alds[t % 3][q * 8]), 16, 0, 0);
                }
            };
            stageA(0); stageA(1);
            wait_vm<2>();
            __builtin_amdgcn_s_barrier();
            f32x16 acc = {};
            for (int t = 0; t < T; ++t) {
                if (t + 2 < T) stageA(t + 2);
                const short* Ab = &Alds[t % 3][0];
                int mt = t >> 5, tk = t & 31;
                short8v ah = *(const short8v*)(Ab + wid * 512 + loct * 256 + l31 * 8);
                short8v al = *(const short8v*)(Ab + 2048 + wid * 512 + loct * 256 + l31 * 8);
                short8v bh = *(const short8v*)(&Blds[mt][0][(tk * 2 + loct) * 256 + l31 * 8]);
                short8v bl = *(const short8v*)(&Blds[mt][1][(tk * 2 + loct) * 256 + l31 * 8]);
                acc = __builtin_amdgcn_mfma_f32_32x32x16_bf16(ah, bh, acc, 0, 0, 0);
                acc = __builtin_amdgcn_mfma_f32_32x32x16_bf16(ah, bl, acc, 0, 0, 0);
                acc = __builtin_amdgcn_mfma_f32_32x32x16_bf16(al, bh, acc, 0, 0, 0);
                if (t + 2 < T) wait_vm<2>(); else wait_vm<0>();
                __builtin_amdgcn_s_barrier();
            }
            // ---- fused gate (c-state in registers) ----
            const float* bab = cell ? babc1 : babc0;
            float* cr = cell ? c2r : c1r;
            short* hdst = cell ? h2out : h1out;
            #pragma unroll
            for (int ug = 0; ug < 4; ++ug) {
                int u = ub + 2 * ug;
                float4 bv = *(const float4*)&bab[4 * u];
                float gi = acc[4 * ug + 0] + bv.x;
                float gf = acc[4 * ug + 1] + bv.y;
                float gg = acc[4 * ug + 2] + bv.z;
                float go = acc[4 * ug + 3] + bv.w;
                cr[ug] = sigmoidf_(gf) * cr[ug] + sigmoidf_(gi) * tanhf(gg);
                float h = sigmoidf_(go) * tanhf(cr[ug]);
                unsigned int p01 = pack2(h);
                size_t o = offf(col, u);
                store2_coh((unsigned short*)(hdst + o), p01 & 0xffffu);
                store2_coh((unsigned short*)(hdst + PABc + o), p01 >> 16);
                if (cell == 1) {
                    int np = col * 16 + s;
                    size_t oc = offf(np, u);
                    condp[oc] = (short)(p01 & 0xffffu);
                    condp[PA4c + oc] = (short)(p01 >> 16);
                }
            }
            devbar2(bar, (++gen) * 128);
        }
    }
}

// ================= merged decoder step: k1(t) || k2(t-1) + logits(t-2)/softmax(t-3) riders ============
struct DecArgs {
    const short *dWhh0P, *dWih1P, *dWhh1P, *WoP;
    const float *babd0, *babd1, *bo;
    const unsigned int *hgP, *embT;
    const int* x;
    float *c0T, *c1dT;
    short *h0a, *h0b, *h1da, *h1db;
    float *LgA, *LgB;
    float* out;
    int t;
};

__global__ __launch_bounds__(512, 1) void dec_step(DecArgs A)
{
    __shared__ __align__(16) short lds[3 * 48 * 512];
    const int role = blockIdx.x >> 8;
    const int dd = blockIdx.x & 255;
    const int t = A.t;
    short* h0[2]  = { A.h0a, A.h0b };
    short* h1d[2] = { A.h1da, A.h1db };
    float* Lg[2]  = { A.LgA, A.LgB };

    if (role == 0) {
        if (t <= 15) {
            int pin = t & 1;
            int bx, by; xswz(dd, 32, 8, bx, by);
            f32x16 acc[2][2];
            gemm_core<2, 2, 3, false>(A.dWhh0P, h0[pin], nullptr, nullptr, 2048, 4096, 16, 100, bx, by, lds, acc);
            epi_gate2<2, 2>(acc, bx, by, 4096, lds, A.babd0, A.hgP,
                            t > 0 ? A.embT : nullptr, t > 0 ? A.x + (t - 1) : nullptr,
                            A.c0T, h0[pin ^ 1], PA4c);
            __syncthreads();
        }
        if (t >= 2 && t <= 17) {
            int k = t - 2;
            int bx, by; xswz(dd, 64, 4, bx, by);
            f32x16 acc1[1][1];
            gemm_core<1, 1, 3, false>(A.WoP, h1d[(k + 1) & 1], nullptr, nullptr, 512, 4096, 16, 100, bx, by, lds, acc1);
            epi_f32<1, 1>(acc1, bx, by, 4096, Lg[k & 1], nullptr, 0);
        }
    } else {
        if (t >= 1 && t <= 16) {
            int s = t - 1;
            int pin2 = s & 1;
            int bx, by; xswz(dd, 32, 8, bx, by);
            f32x16 acc[2][2];
            gemm_core<2, 2, 3, false>(A.dWih1P, h0[(s + 1) & 1], A.dWhh1P, h1d[pin2],
                                      2048, 4096, 32, 16, bx, by, lds, acc);
            epi_gate2<2, 2>(acc, bx, by, 4096, lds, A.babd1, nullptr, nullptr, nullptr,
                            A.c1dT, h1d[pin2 ^ 1], PA4c);
            __syncthreads();
        }
        if (t >= 3) {
            int k = t - 3;
            const float* Lsrc = Lg[k & 1];
            float* tile = (float*)lds;
            float* red  = (float*)lds + 16 * 513;
            float* red2 = red + 512;
            const int tid = threadIdx.x;
            const int mj = tid & 15, vs = tid >> 4;
            const int m = dd * 16 + mj;
            float lv[16];
            #pragma unroll
            for (int i = 0; i < 16; ++i) {
                int v = vs * 16 + i;
                lv[i] = Lsrc[(size_t)v * 4096 + m] + A.bo[v];
            }
            float mx = lv[0];
            #pragma unroll
            for (int i = 1; i < 16; ++i) mx = fmaxf(mx, lv[i]);
            red[vs * 16 + mj] = mx;
            __syncthreads();
            for (int o = 16; o >= 1; o >>= 1) {
                if (vs < o) red[vs * 16 + mj] = fmaxf(red[vs * 16 + mj], red[(vs + o) * 16 + mj]);
                __syncthreads();
            }
            mx = red[mj];
            float sum = 0.f;
            #pragma unroll
            for (int i = 0; i < 16; ++i) {
                float e = expf(lv[i] - mx);
                sum += e;
                tile[mj * 513 + vs * 16 + i] = e;
            }
            red2[vs * 16 + mj] = sum;
            __syncthreads();
            for (int o = 16; o >= 1; o >>= 1) {
                if (vs < o) red2[vs * 16 + mj] += red2[(vs + o) * 16 + mj];
                __syncthreads();
            }
            const int r = tid >> 5, c = tid & 31;
            float invr = 1.f / red2[r];
            for (int kk = 0; kk < 16; ++kk) {
                int v = kk * 32 + c;
                A.out[((size_t)(dd * 16 + r) * 16 + k) * 512 + v] = tile[r * 513 + v] * invr;
            }
        }
    }
}

// ================= one-shot prep =================
struct PrepEnt { const float* src; const float* src2; void* dst; int ldw, col0, perm, total, op; };
struct PrepArgs { PrepEnt e[18]; int n; };

__global__ void prep_all(PrepArgs pa)
{
    for (int ei = 0; ei < pa.n; ++ei) {
        PrepEnt E = pa.e[ei];
        for (int o = blockIdx.x * 256 + threadIdx.x; o < E.total; o += gridDim.x * 256) {
            if (E.op == 0) {
                int c = o >> 8, w = o & 255, r = w >> 3, jj = w & 7;
                int n = (c >> 6) * 32 + r, k = (c & 63) * 8 + jj;
                int nsrc = E.perm ? ((n >> 2) + 512 * (n & 3)) : n;
                float v = E.src[(size_t)nsrc * E.ldw + E.col0 + k];
                unsigned int b0 = f2bfu(v);
                short* pl = (short*)E.dst;
                pl[o] = (short)b0;
                pl[E.total + o] = (short)f2bfu(v - bf2f(b0));
            } else {
                int src = (o >> 2) + 512 * (o & 3);
                ((float*)E.dst)[o] = E.src[src] + E.src2[src];
            }
        }
    }
}

// ================= host =================
extern "C" void kernel_launch(void* const* d_in, const int* in_sizes, int n_in,
                              void* d_out, int out_size, void* d_ws, size_t ws_size,
                              hipStream_t stream)
{
    const float* z     = (const float*)d_in[0];
    const int*   x     = (const int*)  d_in[1];
    const float* Wc    = (const float*)d_in[2];
    const float* bc    = (const float*)d_in[3];
    const float* cWih0 = (const float*)d_in[4];
    const float* cWhh0 = (const float*)d_in[5];
    const float* cbih0 = (const float*)d_in[6];
    const float* cbhh0 = (const float*)d_in[7];
    const float* cWih1 = (const float*)d_in[8];
    const float* cWhh1 = (const float*)d_in[9];
    const float* cbih1 = (const float*)d_in[10];
    const float* cbhh1 = (const float*)d_in[11];
    const float* Wd    = (const float*)d_in[12];
    const float* bd    = (const float*)d_in[13];
    const float* dWih0 = (const float*)d_in[14];
    const float* dWhh0 = (const float*)d_in[15];
    const float* dbih0 = (const float*)d_in[16];
    const float* dbhh0 = (const float*)d_in[17];
    const float* dWih1 = (const float*)d_in[18];
    const float* dWhh1 = (const float*)d_in[19];
    const float* dbih1 = (const float*)d_in[20];
    const float* dbhh1 = (const float*)d_in[21];
    const float* emb   = (const float*)d_in[22];
    const float* Wo    = (const float*)d_in[23];
    const float* bo    = (const float*)d_in[24];
    float* out = (float*)d_out;
    (void)in_sizes; (void)n_in; (void)out_size; (void)ws_size;

    char* wsb = (char*)d_ws;
    size_t off = 0;
    auto alloc = [&](size_t bytes) -> void* {
        off = (off + 255) & ~(size_t)255;
        void* p = wsb + off;
        off += bytes;
        return p;
    };
    const size_t PW  = (size_t)2048 * 512;
    const size_t PWo = (size_t)512 * 512;

    short* WcP    = (short*)alloc(2 * PW * 2);
    short* WdP    = (short*)alloc(2 * PW * 2);
    short* dW1P   = (short*)alloc(2 * PW * 2);
    short* dW2P   = (short*)alloc(2 * PW * 2);
    short* cWih0P = (short*)alloc(2 * PW * 2);
    short* cWhh0P = (short*)alloc(2 * PW * 2);
    short* cWih1P = (short*)alloc(2 * PW * 2);
    short* cWhh1P = (short*)alloc(2 * PW * 2);
    short* dWhh0P = (short*)alloc(2 * PW * 2);
    short* dWih1P = (short*)alloc(2 * PW * 2);
    short* dWhh1P = (short*)alloc(2 * PW * 2);
    short* WoP    = (short*)alloc(2 * PWo * 2);
    short* zpl    = (short*)alloc(2 * PABc * 2);
    short* embpl  = (short*)alloc(2 * PWo * 2);
    float* babc0  = (float*)alloc(2048 * 4);
    float* babc1  = (float*)alloc(2048 * 4);
    float* babd0  = (float*)alloc(2048 * 4);
    float* babd1  = (float*)alloc(2048 * 4);
    float* GbufT  = (float*)alloc((size_t)2048 * 4096 * 4);
    unsigned int* hinitgP = (unsigned int*)alloc((size_t)512 * 4096 * 4 * 4);
    unsigned int* embW0P  = (unsigned int*)alloc((size_t)512 * 512 * 4 * 4);
    short* h1pl0 = (short*)alloc(2 * PABc * 2);
    short* h1pl1 = (short*)alloc(2 * PABc * 2);
    short* h2pl0 = (short*)alloc(2 * PABc * 2);
    short* h2pl1 = (short*)alloc(2 * PABc * 2);
    float* c1T = (float*)alloc((size_t)512 * 256 * 4);
    float* c2T = (float*)alloc((size_t)512 * 256 * 4);
    short* condpl = (short*)alloc(2 * PA4c * 2);
    short* h0pl[2];  short* h1dpl[2];
    h0pl[0]  = (short*)alloc(2 * PA4c * 2); h0pl[1]  = (short*)alloc(2 * PA4c * 2);
    h1dpl[0] = (short*)alloc(2 * PA4c * 2); h1dpl[1] = (short*)alloc(2 * PA4c * 2);
    float* c0T  = (float*)alloc((size_t)512 * 4096 * 4);
    float* c1dT = (float*)alloc((size_t)512 * 4096 * 4);
    unsigned int* barreg = (unsigned int*)alloc(512);

    float* Lg[2] = { GbufT, GbufT + (size_t)512 * 4096 };

    // ---- prep ----
    PrepArgs pa; pa.n = 18;
    auto W8 = [](const float* s, void* d, int ldw, int col0, int perm, int total) {
        PrepEnt e; e.src = s; e.src2 = nullptr; e.dst = d; e.ldw = ldw; e.col0 = col0;
        e.perm = perm; e.total = total; e.op = 0; return e;
    };
    auto B8 = [](const float* a, const float* b, void* d) {
        PrepEnt e; e.src = a; e.src2 = b; e.dst = d; e.ldw = 0; e.col0 = 0;
        e.perm = 0; e.total = 2048; e.op = 1; return e;
    };
    pa.e[0]  = W8(Wc,    WcP,    512,  0,   0, 2048 * 512);
    pa.e[1]  = W8(Wd,    WdP,    512,  0,   0, 2048 * 512);
    pa.e[2]  = W8(dWih0, dW1P,   1024, 0,   1, 2048 * 512);
    pa.e[3]  = W8(dWih0, dW2P,   1024, 512, 1, 2048 * 512);
    pa.e[4]  = W8(cWih0, cWih0P, 512,  0,   1, 2048 * 512);
    pa.e[5]  = W8(cWhh0, cWhh0P, 512,  0,   1, 2048 * 512);
    pa.e[6]  = W8(cWih1, cWih1P, 512,  0,   1, 2048 * 512);
    pa.e[7]  = W8(cWhh1, cWhh1P, 512,  0,   1, 2048 * 512);
    pa.e[8]  = W8(dWhh0, dWhh0P, 512,  0,   1, 2048 * 512);
    pa.e[9]  = W8(dWih1, dWih1P, 512,  0,   1, 2048 * 512);
    pa.e[10] = W8(dWhh1, dWhh1P, 512,  0,   1, 2048 * 512);
    pa.e[11] = W8(Wo,    WoP,    512,  0,   0, 512 * 512);
    pa.e[12] = W8(z,     zpl,    512,  0,   0, 256 * 512);
    pa.e[13] = W8(emb,   embpl,  512,  0,   0, 512 * 512);
    pa.e[14] = B8(cbih0, cbhh0, babc0);
    pa.e[15] = B8(cbih1, cbhh1, babc1);
    pa.e[16] = B8(dbih0, dbhh0, babd0);
    pa.e[17] = B8(dbih1, dbhh1, babd1);
    prep_all<<<dim3(1024), dim3(256), 0, stream>>>(pa);
    hipMemsetAsync(barreg, 0, 512, stream);

    // Phase A: ci = tanh(Wc . z^T + bc) -> h1/h2 planes + c1T/c2T directly
    gemm_split<2, 2><<<dim3(2, 8), dim3(512), 0, stream>>>(
        WcP, zpl, 2048, 256, 16, bc, h1pl0, h2pl0, PABc, c1T, c2T);

    // embW0P = dW1 . emb^T (packed gate table [u][tok][4])
    gemm_packk<2, 2><<<dim3(4, 8), dim3(512), 0, stream>>>(
        dW1P, embpl, nullptr, nullptr, 2048, 512, 16, 100, embW0P);

    // Phase B: persistent conditioning LSTM v4 (128 blocks, B-burst LDS, reg c-state)
    cond_lstm<<<dim3(128), dim3(256), 0, stream>>>(
        cWih0P, cWhh0P, cWih1P, cWhh1P, babc0, babc1, c1T, c2T,
        h1pl0, h1pl1, h2pl0, h2pl1, condpl, barreg);

    // Phase C: states = tanh(Wd . cond^T + bd) -> h0/h1d planes + c0T/c1dT directly
    gemm_split<2, 2><<<dim3(32, 8), dim3(512), 0, stream>>>(
        WdP, condpl, 2048, 4096, 16, bd, h0pl[0], h1dpl[0], PA4c, c0T, c1dT);

    // hinitgP = dW2 . (h0+h1d)^T via dual pair (packed [u][m][4])
    gemm_packk<2, 2><<<dim3(32, 8), dim3(512), 0, stream>>>(
        dW2P, h0pl[0], dW2P, h1dpl[0], 2048, 4096, 32, 16, hinitgP);

    // Phase D: 19 merged launches: k1(t) || k2(t-1) + logits(t-2) + softmax(t-3)
    for (int t = 0; t <= 18; ++t) {
        DecArgs A;
        A.dWhh0P = dWhh0P; A.dWih1P = dWih1P; A.dWhh1P = dWhh1P; A.WoP = WoP;
        A.babd0 = babd0; A.babd1 = babd1; A.bo = bo;
        A.hgP = hinitgP; A.embT = embW0P; A.x = x;
        A.c0T = c0T; A.c1dT = c1dT;
        A.h0a = h0pl[0]; A.h0b = h0pl[1]; A.h1da = h1dpl[0]; A.h1db = h1dpl[1];
        A.LgA = Lg[0]; A.LgB = Lg[1];
        A.out = out; A.t = t;
        dec_step<<<dim3(512), dim3(512), 0, stream>>>(A);
    }
}

// Round 9
// 2400.624 us; speedup vs baseline: 1.2845x; 1.2845x over previous
//
#include <hip/hip_runtime.h>
#include <math.h>

#define AS1 __attribute__((address_space(1)))
#define AS3 __attribute__((address_space(3)))

typedef __attribute__((ext_vector_type(8))) short short8v;
typedef __attribute__((ext_vector_type(16))) float f32x16;

constexpr size_t PA4c = (size_t)4096 * 512;   // plane stride, M=4096 activations
constexpr size_t PABc = (size_t)256 * 512;    // plane stride, M=256 activations

__device__ __forceinline__ float sigmoidf_(float x) { return 1.f / (1.f + expf(-x)); }
__device__ __forceinline__ unsigned int f2bfu(float f) {
    unsigned int u = __float_as_uint(f);
    return (u + 0x7FFF + ((u >> 16) & 1)) >> 16;
}
__device__ __forceinline__ float bf2f(unsigned int s) { return __uint_as_float(s << 16); }
__device__ __forceinline__ unsigned int pack2(float v) {
    unsigned int b0 = f2bfu(v);
    unsigned int b1 = f2bfu(v - bf2f(b0));
    return b0 | (b1 << 16);
}
__device__ __forceinline__ float unpack2(unsigned int p) { return bf2f(p & 0xffffu) + bf2f(p >> 16); }

__device__ __forceinline__ void xswz(int d, int ngx, int ngy, int& bx, int& by) {
    int nwg = ngx * ngy;
    int q = nwg >> 3, r = nwg & 7, xcd = d & 7, pos = d >> 3;
    int logical = (xcd < r ? xcd * (q + 1) : r * (q + 1) + (xcd - r) * q) + pos;
    bx = logical % ngx; by = logical / ngx;
}

// blocked activation-plane offset for (m, k)
__device__ __forceinline__ size_t offf(int m, int k) {
    return ((size_t)((m >> 5) * 64 + (k >> 3))) * 256 + (size_t)((m & 31) * 8 + (k & 7));
}

template<int N>
__device__ __forceinline__ void wait_vm() {
    asm volatile("s_waitcnt vmcnt(%0) lgkmcnt(0)" :: "n"(N) : "memory");
}

// ================= GEMM core: 2-plane/3-product, 8 waves (4m x 2n), BK=32, 3-buffer counted vmcnt ====
template<int FM, int FN>
__device__ __forceinline__ void gemm_core(
    const short* __restrict__ A1, const short* __restrict__ B1,
    const short* __restrict__ A2, const short* __restrict__ B2,
    int M, int N, int nsteps, int pairSwitch,
    int bx, int by, short* lds, f32x16 (&acc)[FM][FN])
{
    constexpr int ABLK = 4 * FM, BBLK = 2 * FN;
    constexpr int ACH = 2 * ABLK * 2, BCH = 2 * BBLK * 2;
    constexpr int CHT = ACH + BCH;
    constexpr int CPW = CHT / 8;
    constexpr int NBUF = 3;
    constexpr int BUFSH = CHT * 512;
    const int tid = threadIdx.x, lane = tid & 63, wid = tid >> 6;
    const int wm = wid >> 1, wn = wid & 1;
    const int l31 = lane & 31, loct = lane >> 5;
    const int mblk0 = by * ABLK, nblk0 = bx * BBLK;
    const size_t planeA = (size_t)M * 512, planeB = (size_t)N * 512;

    const short* cur[CPW];
    const short* nxt[CPW];
    int ldo[CPW];
    #pragma unroll
    for (int i = 0; i < CPW; ++i) {
        int c = wid * CPW + i;
        ldo[i] = c * 512;
        size_t off;
        const short *b1, *b2;
        if (c < ACH) {
            int plane = c / (ABLK * 2), rem = c % (ABLK * 2), blk = rem >> 1, piece = rem & 1;
            off = (size_t)plane * planeA + (size_t)(mblk0 + blk) * 16384 + piece * 512 + lane * 8;
            b1 = A1; b2 = A2;
        } else {
            int cb = c - ACH;
            int plane = cb / (BBLK * 2), rem = cb % (BBLK * 2), blk = rem >> 1, piece = rem & 1;
            off = (size_t)plane * planeB + (size_t)(nblk0 + blk) * 16384 + piece * 512 + lane * 8;
            b1 = B1; b2 = B2;
        }
        cur[i] = b1 + off;
        nxt[i] = b2 ? (b2 + off) : (b1 + off);
    }

    #pragma unroll
    for (int fm = 0; fm < FM; ++fm)
        #pragma unroll
        for (int fn = 0; fn < FN; ++fn)
            acc[fm][fn] = (f32x16){};

    auto STAGE = [&](int bufIdx) {
        short* db = lds + bufIdx * BUFSH;
        #pragma unroll
        for (int i = 0; i < CPW; ++i) {
            __builtin_amdgcn_global_load_lds((const AS1 unsigned int*)cur[i],
                                             (AS3 unsigned int*)(db + ldo[i]), 16, 0, 0);
            cur[i] += 1024;
        }
    };

    STAGE(0); STAGE(1);
    wait_vm<CPW>();
    __builtin_amdgcn_s_barrier();

    for (int t = 0; t < nsteps; ++t) {
        int s = t + NBUF - 1;
        if (s < nsteps) {
            if (s == pairSwitch) {
                #pragma unroll
                for (int i = 0; i < CPW; ++i) cur[i] = nxt[i];
            }
            STAGE(s % NBUF);
        }
        const short* L = lds + (t % NBUF) * BUFSH;
        #pragma unroll
        for (int ksub = 0; ksub < 2; ++ksub) {
            short8v a[FM][2], b[FN][2];
            #pragma unroll
            for (int p = 0; p < 2; ++p) {
                #pragma unroll
                for (int f = 0; f < FM; ++f)
                    a[f][p] = *(const short8v*)(L + (p * (ABLK * 2) + (wm * FM + f) * 2 + ksub) * 512
                                                  + loct * 256 + l31 * 8);
                #pragma unroll
                for (int f = 0; f < FN; ++f)
                    b[f][p] = *(const short8v*)(L + (ACH + p * (BBLK * 2) + (wn * FN + f) * 2 + ksub) * 512
                                                  + loct * 256 + l31 * 8);
            }
            #pragma unroll
            for (int pp = 0; pp < 3; ++pp) {
                const int pa = (pp == 2) ? 1 : 0, pb = (pp == 1) ? 1 : 0;
                #pragma unroll
                for (int fm = 0; fm < FM; ++fm)
                    #pragma unroll
                    for (int fn = 0; fn < FN; ++fn)
                        acc[fm][fn] = __builtin_amdgcn_mfma_f32_32x32x16_bf16(
                            a[fm][pa], b[fn][pb], acc[fm][fn], 0, 0, 0);
            }
        }
        if (t + 2 < nsteps) wait_vm<CPW>();
        else                wait_vm<0>();
        __builtin_amdgcn_s_barrier();
    }
}

// ---------------- epilogues (C/D layout: col=lane&31, row=(reg&3)+8*(reg>>2)+4*(lane>>5)) ----------------
template<int FM, int FN>
__device__ __forceinline__ void epi_f32(f32x16 (&acc)[FM][FN], int bx, int by, int N,
                                        float* __restrict__ Cout, const float* __restrict__ bias, int act)
{
    constexpr int ROWS = 128 * FM, COLS = 64 * FN;
    const int tid = threadIdx.x, lane = tid & 63, wid = tid >> 6;
    const int wm = wid >> 1, wn = wid & 1, l31 = lane & 31, loct = lane >> 5;
    #pragma unroll
    for (int fm = 0; fm < FM; ++fm)
        #pragma unroll
        for (int fn = 0; fn < FN; ++fn) {
            int col = bx * COLS + wn * FN * 32 + fn * 32 + l31;
            int rb  = by * ROWS + wm * FM * 32 + fm * 32 + 4 * loct;
            #pragma unroll
            for (int reg = 0; reg < 16; ++reg) {
                int row = rb + (reg & 3) + 8 * (reg >> 2);
                float xv = acc[fm][fn][reg] + (bias ? bias[row] : 0.f);
                if (act) xv = tanhf(xv);
                Cout[(size_t)row * N + col] = xv;
            }
        }
}

template<int FM, int FN>
__device__ __forceinline__ void epi_pack(f32x16 (&acc)[FM][FN], int bx, int by, int N,
                                         unsigned int* __restrict__ packOut)
{
    constexpr int ROWS = 128 * FM, COLS = 64 * FN;
    const int tid = threadIdx.x, lane = tid & 63, wid = tid >> 6;
    const int wm = wid >> 1, wn = wid & 1, l31 = lane & 31, loct = lane >> 5;
    uint4* P4 = (uint4*)packOut;
    #pragma unroll
    for (int fm = 0; fm < FM; ++fm)
        #pragma unroll
        for (int fn = 0; fn < FN; ++fn) {
            int col = bx * COLS + wn * FN * 32 + fn * 32 + l31;
            int ub = by * (ROWS / 4) + wm * FM * 8 + fm * 8 + loct;
            #pragma unroll
            for (int ug = 0; ug < 4; ++ug) {
                int u = ub + 2 * ug;
                uint4 v;
                v.x = pack2(acc[fm][fn][4 * ug + 0]);
                v.y = pack2(acc[fm][fn][4 * ug + 1]);
                v.z = pack2(acc[fm][fn][4 * ug + 2]);
                v.w = pack2(acc[fm][fn][4 * ug + 3]);
                P4[(size_t)u * N + col] = v;
            }
        }
}

// fused LSTM gate epilogue, batched loads; optional condp copy (phase B cell 2)
template<int FM, int FN>
__device__ __forceinline__ void epi_gate2(
    f32x16 (&acc)[FM][FN], int bx, int by, int N, short* hl,
    const float* __restrict__ bab,
    const unsigned int* __restrict__ hgP,
    const unsigned int* __restrict__ embT,
    const int* __restrict__ xidx,
    float* __restrict__ cT,
    short* __restrict__ hout, size_t hps,
    short* __restrict__ condp, int ustep)
{
    constexpr int ABLK = 4 * FM, BBLK = 2 * FN;
    constexpr int ROWS = 32 * ABLK, COLS = 32 * BBLK;
    constexpr int CHN = ABLK * BBLK * 256;
    const int tid = threadIdx.x, lane = tid & 63, wid = tid >> 6;
    const int wm = wid >> 1, wn = wid & 1, l31 = lane & 31, loct = lane >> 5;
    #pragma unroll
    for (int fm = 0; fm < FM; ++fm) {
        #pragma unroll
        for (int fn = 0; fn < FN; ++fn) {
            const int col = bx * COLS + wn * FN * 32 + fn * 32 + l31;
            const int ub = by * (ROWS / 4) + wm * FM * 8 + fm * 8 + loct;
            int tok = -1;
            if (xidx) tok = xidx[(size_t)col * 16];
            uint4 hv[4]; uint4 ev[4]; float cv[4]; float4 bv[4];
            #pragma unroll
            for (int ug = 0; ug < 4; ++ug) {
                int u = ub + 2 * ug;
                bv[ug] = *(const float4*)&bab[4 * u];
                cv[ug] = cT[(size_t)u * N + col];
                if (hgP) hv[ug] = ((const uint4*)hgP)[(size_t)u * N + col];
            }
            if (embT && tok >= 0) {
                #pragma unroll
                for (int ug = 0; ug < 4; ++ug) {
                    int u = ub + 2 * ug;
                    ev[ug] = ((const uint4*)embT)[(size_t)u * 512 + tok];
                }
            }
            #pragma unroll
            for (int ug = 0; ug < 4; ++ug) {
                int u = ub + 2 * ug;
                float gi = acc[fm][fn][4 * ug + 0] + bv[ug].x;
                float gf = acc[fm][fn][4 * ug + 1] + bv[ug].y;
                float gg = acc[fm][fn][4 * ug + 2] + bv[ug].z;
                float go = acc[fm][fn][4 * ug + 3] + bv[ug].w;
                if (hgP) {
                    gi += unpack2(hv[ug].x); gf += unpack2(hv[ug].y);
                    gg += unpack2(hv[ug].z); go += unpack2(hv[ug].w);
                }
                if (embT && tok >= 0) {
                    gi += unpack2(ev[ug].x); gf += unpack2(ev[ug].y);
                    gg += unpack2(ev[ug].z); go += unpack2(ev[ug].w);
                }
                float c = sigmoidf_(gf) * cv[ug] + sigmoidf_(gi) * tanhf(gg);
                cT[(size_t)u * N + col] = c;
                float h = sigmoidf_(go) * tanhf(c);
                unsigned int p01 = pack2(h);
                int u_loc = wm * FM * 8 + fm * 8 + loct + 2 * ug;
                int m_loc = wn * FN * 32 + fn * 32 + l31;
                int offl = ((m_loc >> 5) * ABLK + (u_loc >> 3)) * 256 + (m_loc & 31) * 8 + (u_loc & 7);
                hl[offl] = (short)(p01 & 0xffffu);
                hl[CHN + offl] = (short)(p01 >> 16);
                if (condp) {
                    int np = col * 16 + ustep;
                    size_t oc = offf(np, u);
                    condp[oc] = (short)(p01 & 0xffffu);
                    condp[PA4c + oc] = (short)(p01 >> 16);
                }
            }
        }
    }
    __syncthreads();
    constexpr int LB = (ABLK == 8) ? 3 : 2;
    for (int p = 0; p < 2; ++p) {
        for (int jj = tid; jj < CHN / 8; jj += 512) {
            int lc = jj >> 5, m31 = jj & 31;
            int m5 = lc >> LB, u3 = lc & (ABLK - 1);
            size_t gc = (size_t)((bx * BBLK + m5) * 64 + by * ABLK + u3);
            *(short8v*)(hout + p * hps + gc * 256 + m31 * 8) = *(const short8v*)(hl + p * CHN + jj * 8);
        }
    }
}

// ================= standalone GEMM kernels =================
template<int FM, int FN>
__global__ __launch_bounds__(512, 1) void gemm_packk(
    const short* A1, const short* B1, const short* A2, const short* B2,
    int M, int N, int nsteps, int psw, unsigned int* packOut)
{
    __shared__ __align__(16) short lds[3 * (2 * (4 * FM) * 2 + 2 * (2 * FN) * 2) * 512];
    int d = blockIdx.y * gridDim.x + blockIdx.x;
    int bx, by; xswz(d, gridDim.x, gridDim.y, bx, by);
    f32x16 acc[FM][FN];
    gemm_core<FM, FN>(A1, B1, A2, B2, M, N, nsteps, psw, bx, by, lds, acc);
    epi_pack<FM, FN>(acc, bx, by, N, packOut);
}

template<int FM, int FN>
__global__ __launch_bounds__(512, 1) void gemm_split(
    const short* A1, const short* B1, int M, int N, int nsteps,
    const float* bias, short* hA, short* hB, size_t ps, float* cA, float* cB)
{
    __shared__ __align__(16) short lds[3 * (2 * (4 * FM) * 2 + 2 * (2 * FN) * 2) * 512];
    int d = blockIdx.y * gridDim.x + blockIdx.x;
    int bx, by; xswz(d, gridDim.x, gridDim.y, bx, by);
    f32x16 acc[FM][FN];
    gemm_core<FM, FN>(A1, B1, nullptr, nullptr, M, N, nsteps, 100, bx, by, lds, acc);
    constexpr int ROWS = 128 * FM, COLS = 64 * FN;
    const int tid = threadIdx.x, lane = tid & 63, wid = tid >> 6;
    const int wm = wid >> 1, wn = wid & 1, l31 = lane & 31, loct = lane >> 5;
    #pragma unroll
    for (int fm = 0; fm < FM; ++fm)
        #pragma unroll
        for (int fn = 0; fn < FN; ++fn) {
            int col = bx * COLS + wn * FN * 32 + fn * 32 + l31;
            int rb  = by * ROWS + wm * FM * 32 + fm * 32 + 4 * loct;
            #pragma unroll
            for (int reg = 0; reg < 16; ++reg) {
                int row = rb + (reg & 3) + 8 * (reg >> 2);
                float xv = tanhf(acc[fm][fn][reg] + bias[row]);
                if (row < 1024) {
                    short* hp = (row < 512) ? hA : hB;
                    size_t o = offf(col, row & 511);
                    unsigned int p01 = pack2(xv);
                    hp[o] = (short)(p01 & 0xffffu);
                    hp[ps + o] = (short)(p01 >> 16);
                } else {
                    float* cp = (row < 1536) ? cA : cB;
                    cp[(size_t)(row & 511) * N + col] = xv;
                }
            }
        }
}

// ================= phase B: one conditioning-LSTM cell per launch (fused GEMM + gate) =================
__global__ __launch_bounds__(512, 1) void cond_cell(
    const short* A1, const short* B1, const short* A2, const short* B2,
    int nsteps, int psw,
    const float* bab, float* cT,
    short* hout, short* condp, int ustep)
{
    __shared__ __align__(16) short lds[3 * 24 * 512];   // FM=1,FN=1: 72 KB
    int d = blockIdx.y * gridDim.x + blockIdx.x;
    int bx, by; xswz(d, gridDim.x, gridDim.y, bx, by);
    f32x16 acc[1][1];
    gemm_core<1, 1>(A1, B1, A2, B2, 2048, 256, nsteps, psw, bx, by, lds, acc);
    epi_gate2<1, 1>(acc, bx, by, 256, lds, bab, nullptr, nullptr, nullptr,
                    cT, hout, PABc, condp, ustep);
}

// ================= merged decoder step: k1(t) || k2(t-1) + logits(t-2)/softmax(t-3) riders ============
struct DecArgs {
    const short *dWhh0P, *dWih1P, *dWhh1P, *WoP;
    const float *babd0, *babd1, *bo;
    const unsigned int *hgP, *embT;
    const int* x;
    float *c0T, *c1dT;
    short *h0a, *h0b, *h1da, *h1db;
    float *LgA, *LgB;
    float* out;
    int t;
};

__global__ __launch_bounds__(512, 1) void dec_step(DecArgs A)
{
    __shared__ __align__(16) short lds[3 * 48 * 512];
    const int role = blockIdx.x >> 8;
    const int dd = blockIdx.x & 255;
    const int t = A.t;
    short* h0[2]  = { A.h0a, A.h0b };
    short* h1d[2] = { A.h1da, A.h1db };
    float* Lg[2]  = { A.LgA, A.LgB };

    if (role == 0) {
        if (t <= 15) {
            int pin = t & 1;
            int bx, by; xswz(dd, 32, 8, bx, by);
            f32x16 acc[2][2];
            gemm_core<2, 2>(A.dWhh0P, h0[pin], nullptr, nullptr, 2048, 4096, 16, 100, bx, by, lds, acc);
            epi_gate2<2, 2>(acc, bx, by, 4096, lds, A.babd0, A.hgP,
                            t > 0 ? A.embT : nullptr, t > 0 ? A.x + (t - 1) : nullptr,
                            A.c0T, h0[pin ^ 1], PA4c, nullptr, 0);
            __syncthreads();
        }
        if (t >= 2 && t <= 17) {
            int k = t - 2;
            int bx, by; xswz(dd, 64, 4, bx, by);
            f32x16 acc1[1][1];
            gemm_core<1, 1>(A.WoP, h1d[(k + 1) & 1], nullptr, nullptr, 512, 4096, 16, 100, bx, by, lds, acc1);
            epi_f32<1, 1>(acc1, bx, by, 4096, Lg[k & 1], nullptr, 0);
        }
    } else {
        if (t >= 1 && t <= 16) {
            int s = t - 1;
            int pin2 = s & 1;
            int bx, by; xswz(dd, 32, 8, bx, by);
            f32x16 acc[2][2];
            gemm_core<2, 2>(A.dWih1P, h0[(s + 1) & 1], A.dWhh1P, h1d[pin2],
                            2048, 4096, 32, 16, bx, by, lds, acc);
            epi_gate2<2, 2>(acc, bx, by, 4096, lds, A.babd1, nullptr, nullptr, nullptr,
                            A.c1dT, h1d[pin2 ^ 1], PA4c, nullptr, 0);
            __syncthreads();
        }
        if (t >= 3) {
            int k = t - 3;
            const float* Lsrc = Lg[k & 1];
            float* tile = (float*)lds;
            float* red  = (float*)lds + 16 * 513;
            float* red2 = red + 512;
            const int tid = threadIdx.x;
            const int mj = tid & 15, vs = tid >> 4;
            const int m = dd * 16 + mj;
            float lv[16];
            #pragma unroll
            for (int i = 0; i < 16; ++i) {
                int v = vs * 16 + i;
                lv[i] = Lsrc[(size_t)v * 4096 + m] + A.bo[v];
            }
            float mx = lv[0];
            #pragma unroll
            for (int i = 1; i < 16; ++i) mx = fmaxf(mx, lv[i]);
            red[vs * 16 + mj] = mx;
            __syncthreads();
            for (int o = 16; o >= 1; o >>= 1) {
                if (vs < o) red[vs * 16 + mj] = fmaxf(red[vs * 16 + mj], red[(vs + o) * 16 + mj]);
                __syncthreads();
            }
            mx = red[mj];
            float sum = 0.f;
            #pragma unroll
            for (int i = 0; i < 16; ++i) {
                float e = expf(lv[i] - mx);
                sum += e;
                tile[mj * 513 + vs * 16 + i] = e;
            }
            red2[vs * 16 + mj] = sum;
            __syncthreads();
            for (int o = 16; o >= 1; o >>= 1) {
                if (vs < o) red2[vs * 16 + mj] += red2[(vs + o) * 16 + mj];
                __syncthreads();
            }
            const int r = tid >> 5, c = tid & 31;
            float invr = 1.f / red2[r];
            for (int kk = 0; kk < 16; ++kk) {
                int v = kk * 32 + c;
                A.out[((size_t)(dd * 16 + r) * 16 + k) * 512 + v] = tile[r * 513 + v] * invr;
            }
        }
    }
}

// ================= one-shot prep =================
struct PrepEnt { const float* src; const float* src2; void* dst; int ldw, col0, perm, total, op; };
struct PrepArgs { PrepEnt e[18]; int n; };

__global__ void prep_all(PrepArgs pa)
{
    for (int ei = 0; ei < pa.n; ++ei) {
        PrepEnt E = pa.e[ei];
        for (int o = blockIdx.x * 256 + threadIdx.x; o < E.total; o += gridDim.x * 256) {
            if (E.op == 0) {
                int c = o >> 8, w = o & 255, r = w >> 3, jj = w & 7;
                int n = (c >> 6) * 32 + r, k = (c & 63) * 8 + jj;
                int nsrc = E.perm ? ((n >> 2) + 512 * (n & 3)) : n;
                float v = E.src[(size_t)nsrc * E.ldw + E.col0 + k];
                unsigned int b0 = f2bfu(v);
                short* pl = (short*)E.dst;
                pl[o] = (short)b0;
                pl[E.total + o] = (short)f2bfu(v - bf2f(b0));
            } else {
                int src = (o >> 2) + 512 * (o & 3);
                ((float*)E.dst)[o] = E.src[src] + E.src2[src];
            }
        }
    }
}

// ================= host =================
extern "C" void kernel_launch(void* const* d_in, const int* in_sizes, int n_in,
                              void* d_out, int out_size, void* d_ws, size_t ws_size,
                              hipStream_t stream)
{
    const float* z     = (const float*)d_in[0];
    const int*   x     = (const int*)  d_in[1];
    const float* Wc    = (const float*)d_in[2];
    const float* bc    = (const float*)d_in[3];
    const float* cWih0 = (const float*)d_in[4];
    const float* cWhh0 = (const float*)d_in[5];
    const float* cbih0 = (const float*)d_in[6];
    const float* cbhh0 = (const float*)d_in[7];
    const float* cWih1 = (const float*)d_in[8];
    const float* cWhh1 = (const float*)d_in[9];
    const float* cbih1 = (const float*)d_in[10];
    const float* cbhh1 = (const float*)d_in[11];
    const float* Wd    = (const float*)d_in[12];
    const float* bd    = (const float*)d_in[13];
    const float* dWih0 = (const float*)d_in[14];
    const float* dWhh0 = (const float*)d_in[15];
    const float* dbih0 = (const float*)d_in[16];
    const float* dbhh0 = (const float*)d_in[17];
    const float* dWih1 = (const float*)d_in[18];
    const float* dWhh1 = (const float*)d_in[19];
    const float* dbih1 = (const float*)d_in[20];
    const float* dbhh1 = (const float*)d_in[21];
    const float* emb   = (const float*)d_in[22];
    const float* Wo    = (const float*)d_in[23];
    const float* bo    = (const float*)d_in[24];
    float* out = (float*)d_out;
    (void)in_sizes; (void)n_in; (void)out_size; (void)ws_size;

    char* wsb = (char*)d_ws;
    size_t off = 0;
    auto alloc = [&](size_t bytes) -> void* {
        off = (off + 255) & ~(size_t)255;
        void* p = wsb + off;
        off += bytes;
        return p;
    };
    const size_t PW  = (size_t)2048 * 512;
    const size_t PWo = (size_t)512 * 512;

    short* WcP    = (short*)alloc(2 * PW * 2);
    short* WdP    = (short*)alloc(2 * PW * 2);
    short* dW1P   = (short*)alloc(2 * PW * 2);
    short* dW2P   = (short*)alloc(2 * PW * 2);
    short* cWih0P = (short*)alloc(2 * PW * 2);
    short* cWhh0P = (short*)alloc(2 * PW * 2);
    short* cWih1P = (short*)alloc(2 * PW * 2);
    short* cWhh1P = (short*)alloc(2 * PW * 2);
    short* dWhh0P = (short*)alloc(2 * PW * 2);
    short* dWih1P = (short*)alloc(2 * PW * 2);
    short* dWhh1P = (short*)alloc(2 * PW * 2);
    short* WoP    = (short*)alloc(2 * PWo * 2);
    short* zpl    = (short*)alloc(2 * PABc * 2);
    short* embpl  = (short*)alloc(2 * PWo * 2);
    float* babc0  = (float*)alloc(2048 * 4);
    float* babc1  = (float*)alloc(2048 * 4);
    float* babd0  = (float*)alloc(2048 * 4);
    float* babd1  = (float*)alloc(2048 * 4);
    float* GbufT  = (float*)alloc((size_t)2048 * 4096 * 4);
    unsigned int* hinitgP = (unsigned int*)alloc((size_t)512 * 4096 * 4 * 4);
    unsigned int* embW0P  = (unsigned int*)alloc((size_t)512 * 512 * 4 * 4);
    short* h1pl[2]; short* h2pl[2];
    h1pl[0] = (short*)alloc(2 * PABc * 2);  h1pl[1] = (short*)alloc(2 * PABc * 2);
    h2pl[0] = (short*)alloc(2 * PABc * 2);  h2pl[1] = (short*)alloc(2 * PABc * 2);
    float* c1T = (float*)alloc((size_t)512 * 256 * 4);
    float* c2T = (float*)alloc((size_t)512 * 256 * 4);
    short* condpl = (short*)alloc(2 * PA4c * 2);
    short* h0pl[2];  short* h1dpl[2];
    h0pl[0]  = (short*)alloc(2 * PA4c * 2); h0pl[1]  = (short*)alloc(2 * PA4c * 2);
    h1dpl[0] = (short*)alloc(2 * PA4c * 2); h1dpl[1] = (short*)alloc(2 * PA4c * 2);
    float* c0T  = (float*)alloc((size_t)512 * 4096 * 4);
    float* c1dT = (float*)alloc((size_t)512 * 4096 * 4);

    float* Lg[2] = { GbufT, GbufT + (size_t)512 * 4096 };

    // ---- prep ----
    PrepArgs pa; pa.n = 18;
    auto W8 = [](const float* s, void* d, int ldw, int col0, int perm, int total) {
        PrepEnt e; e.src = s; e.src2 = nullptr; e.dst = d; e.ldw = ldw; e.col0 = col0;
        e.perm = perm; e.total = total; e.op = 0; return e;
    };
    auto B8 = [](const float* a, const float* b, void* d) {
        PrepEnt e; e.src = a; e.src2 = b; e.dst = d; e.ldw = 0; e.col0 = 0;
        e.perm = 0; e.total = 2048; e.op = 1; return e;
    };
    pa.e[0]  = W8(Wc,    WcP,    512,  0,   0, 2048 * 512);
    pa.e[1]  = W8(Wd,    WdP,    512,  0,   0, 2048 * 512);
    pa.e[2]  = W8(dWih0, dW1P,   1024, 0,   1, 2048 * 512);
    pa.e[3]  = W8(dWih0, dW2P,   1024, 512, 1, 2048 * 512);
    pa.e[4]  = W8(cWih0, cWih0P, 512,  0,   1, 2048 * 512);
    pa.e[5]  = W8(cWhh0, cWhh0P, 512,  0,   1, 2048 * 512);
    pa.e[6]  = W8(cWih1, cWih1P, 512,  0,   1, 2048 * 512);
    pa.e[7]  = W8(cWhh1, cWhh1P, 512,  0,   1, 2048 * 512);
    pa.e[8]  = W8(dWhh0, dWhh0P, 512,  0,   1, 2048 * 512);
    pa.e[9]  = W8(dWih1, dWih1P, 512,  0,   1, 2048 * 512);
    pa.e[10] = W8(dWhh1, dWhh1P, 512,  0,   1, 2048 * 512);
    pa.e[11] = W8(Wo,    WoP,    512,  0,   0, 512 * 512);
    pa.e[12] = W8(z,     zpl,    512,  0,   0, 256 * 512);
    pa.e[13] = W8(emb,   embpl,  512,  0,   0, 512 * 512);
    pa.e[14] = B8(cbih0, cbhh0, babc0);
    pa.e[15] = B8(cbih1, cbhh1, babc1);
    pa.e[16] = B8(dbih0, dbhh0, babd0);
    pa.e[17] = B8(dbih1, dbhh1, babd1);
    prep_all<<<dim3(1024), dim3(256), 0, stream>>>(pa);

    // Phase A: ci = tanh(Wc . z^T + bc) -> h1/h2 planes + c1T/c2T directly
    gemm_split<2, 2><<<dim3(2, 8), dim3(512), 0, stream>>>(
        WcP, zpl, 2048, 256, 16, bc, h1pl[0], h2pl[0], PABc, c1T, c2T);

    // embW0P = dW1 . emb^T (packed gate table [u][tok][4])
    gemm_packk<2, 2><<<dim3(4, 8), dim3(512), 0, stream>>>(
        dW1P, embpl, nullptr, nullptr, 2048, 512, 16, 100, embW0P);

    // Phase B: conditioning LSTM, 32 discrete fused GEMM+gate launches
    for (int u = 0; u < 16; ++u) {
        int pin = u & 1;
        if (u == 0)
            cond_cell<<<dim3(4, 16), dim3(512), 0, stream>>>(
                cWhh0P, h1pl[0], nullptr, nullptr, 16, 100,
                babc0, c1T, h1pl[1], nullptr, 0);
        else
            cond_cell<<<dim3(4, 16), dim3(512), 0, stream>>>(
                cWih0P, h2pl[pin], cWhh0P, h1pl[pin], 32, 16,
                babc0, c1T, h1pl[pin ^ 1], nullptr, 0);
        cond_cell<<<dim3(4, 16), dim3(512), 0, stream>>>(
            cWih1P, h1pl[pin ^ 1], cWhh1P, h2pl[pin], 32, 16,
            babc1, c2T, h2pl[pin ^ 1], condpl, u);
    }

    // Phase C: states = tanh(Wd . cond^T + bd) -> h0/h1d planes + c0T/c1dT directly
    gemm_split<2, 2><<<dim3(32, 8), dim3(512), 0, stream>>>(
        WdP, condpl, 2048, 4096, 16, bd, h0pl[0], h1dpl[0], PA4c, c0T, c1dT);

    // hinitgP = dW2 . (h0+h1d)^T via dual pair (packed [u][m][4])
    gemm_packk<2, 2><<<dim3(32, 8), dim3(512), 0, stream>>>(
        dW2P, h0pl[0], dW2P, h1dpl[0], 2048, 4096, 32, 16, hinitgP);

    // Phase D: 19 merged launches: k1(t) || k2(t-1) + logits(t-2) + softmax(t-3)
    for (int t = 0; t <= 18; ++t) {
        DecArgs A;
        A.dWhh0P = dWhh0P; A.dWih1P = dWih1P; A.dWhh1P = dWhh1P; A.WoP = WoP;
        A.babd0 = babd0; A.babd1 = babd1; A.bo = bo;
        A.hgP = hinitgP; A.embT = embW0P; A.x = x;
        A.c0T = c0T; A.c1dT = c1dT;
        A.h0a = h0pl[0]; A.h0b = h0pl[1]; A.h1da = h1dpl[0]; A.h1db = h1dpl[1];
        A.LgA = Lg[0]; A.LgB = Lg[1];
        A.out = out; A.t = t;
        dec_step<<<dim3(512), dim3(512), 0, stream>>>(A);
    }
}